// Round 10
// baseline (252.661 us; speedup 1.0000x reference)
//
#include <hip/hip_runtime.h>

#define N_NODES 4096
#define D_DIM   512
#define E_EDGES 131072
#define NWORDS  128   // 4096/32
#define AGG_BLOCKS 1024

typedef __bf16 bf16;
typedef __bf16 bf16x4 __attribute__((ext_vector_type(4)));
typedef __bf16 bf16x8 __attribute__((ext_vector_type(8)));
typedef float  f32x4  __attribute__((ext_vector_type(4)));
typedef unsigned int u32;

// async global->LDS, 16 B per lane; LDS dest = wave-uniform base + lane*16
#define GLOAD_LDS16(gp, lp) \
    __builtin_amdgcn_global_load_lds((const __attribute__((address_space(1))) u32*)(gp), \
                                     (__attribute__((address_space(3))) u32*)(lp), 16, 0, 0)

// ---------------- workspace layout ----------------
static const size_t OFF_W1B = 0;                                    // W1 bf16 512 KiB
static const size_t OFF_W2B = OFF_W1B + (size_t)D_DIM*D_DIM*2;
static const size_t OFF_X1  = OFF_W2B + (size_t)D_DIM*D_DIM*2;      // x1 bf16 4 MiB
static const size_t OFF_X2  = OFF_X1  + (size_t)N_NODES*D_DIM*2;    // x2 bf16 4 MiB
static const size_t OFF_ANG = OFF_X2  + (size_t)N_NODES*D_DIM*2;    // angles fp32 (init bo in g0 tail)
static const size_t OFF_H1  = OFF_ANG + N_NODES*4;                  // hop1 accum (carries 0.25)
static const size_t OFF_A2V = OFF_H1  + N_NODES*4;                  // a2 fp32
static const size_t OFF_TP  = OFF_A2V + N_NODES*4;                  // Tpart[1024]
// ---- zero region: barrier counters + A bits (single memset) ----
static const size_t OFF_CTR = OFF_TP  + 1024*4;                     // 256 B (2 counters used)
static const size_t OFF_AB  = OFF_CTR + 256;                        // A bits 2 MiB
static const size_t ZERO_BYTES = 256 + (size_t)N_NODES*NWORDS*4;
static const size_t OFF_A2B = OFF_AB  + (size_t)N_NODES*NWORDS*4;   // A^2 bits
static const size_t OFF_A3B = OFF_A2B + (size_t)N_NODES*NWORDS*4;   // A^3 bits

__device__ __forceinline__ bf16x8 cvt8(float4 lo, float4 hi) {
    bf16x8 r;
    r[0] = (bf16)lo.x; r[1] = (bf16)lo.y; r[2] = (bf16)lo.z; r[3] = (bf16)lo.w;
    r[4] = (bf16)hi.x; r[5] = (bf16)hi.y; r[6] = (bf16)hi.z; r[7] = (bf16)hi.w;
    return r;
}

// manual device-scope grid barrier (NOT cooperative grid.sync — that costs ~106us, r8).
// all AGG_BLOCKS blocks are co-resident (4/CU, cap 8/CU), so spinning is safe.
__device__ __forceinline__ void grid_barrier(u32* cnt) {
    __syncthreads();
    if (threadIdx.x == 0) {
        __threadfence();                              // release: drain writes to L2
        u32 arrived = atomicAdd(cnt, 1u) + 1;
        while (arrived < AGG_BLOCKS) {                // device-scope RMW bypasses L1
            __builtin_amdgcn_s_sleep(1);
            arrived = atomicAdd(cnt, 0u);
        }
    }
    __syncthreads();
}

// ---------------- fused GEMM (+independent work in tail blocks) ----------------
// Tile 64x64, BK=64, double-buffered LDS, 512 gemm blocks, 4 waves (2x2 of 32x32).
// MODE 0: fp32 inputs, register-prefetch + inline cast; tail = adj(128)+Wcast(128)+init(1).
// MODE 1/2: bf16 inputs via global_load_lds; tail = 1024 boolean row-OR blocks.
template<int MODE>
__global__ __launch_bounds__(256)
void gemm_fused(const float* __restrict__ Xf, const float* __restrict__ Wf,   // MODE 0
                const bf16* __restrict__ X, const bf16* __restrict__ W,       // MODE 1/2
                bf16* __restrict__ outB,
                const float* __restrict__ bias, const float* __restrict__ slope,
                const float* __restrict__ Wo, float* __restrict__ ang,
                const float* __restrict__ bo, float* __restrict__ h1,
                const float* __restrict__ W1f, const float* __restrict__ W2f,
                bf16* __restrict__ W1b, bf16* __restrict__ W2b,
                const int* __restrict__ esrc, const int* __restrict__ edst,
                u32* __restrict__ AbOut,
                const u32* __restrict__ P, const u32* __restrict__ Q, u32* __restrict__ BOut)
{
    __shared__ bf16 At[2][64][64];   // 16 KiB (double-buffered)
    __shared__ bf16 Bt[2][64][64];   // 16 KiB
    __shared__ int  s_cnt[4];
    __shared__ int  s_list[4][256];
    const int bx = blockIdx.x;
    const int t = threadIdx.x;
    const int wave = t >> 6, lane = t & 63;

    if (bx < 512) {
        const int wm = wave >> 1, wn = wave & 1;
        const int quad = lane >> 4, lq = lane & 15;
        const int rowBase = (bx >> 3) * 64;
        const int colBase = (bx & 7) * 64;
        const int c0 = t, c1 = t + 256;                 // 512 chunks of 8 elems per tile
        const int r0 = c0 >> 3, o0 = (c0 & 7) * 8;
        const int r1 = c1 >> 3, o1 = (c1 & 7) * 8;

        f32x4 acc[2][2] = {};
        int cur = 0;

        if (MODE == 0) {
            const float* gA0 = Xf + (size_t)(rowBase + r0) * D_DIM + o0;
            const float* gA1 = Xf + (size_t)(rowBase + r1) * D_DIM + o1;
            const float* gB0 = Wf + (size_t)(colBase + r0) * D_DIM + o0;
            const float* gB1 = Wf + (size_t)(colBase + r1) * D_DIM + o1;
            float4 pa0l = *(const float4*)(gA0),     pa0h = *(const float4*)(gA0 + 4);
            float4 pa1l = *(const float4*)(gA1),     pa1h = *(const float4*)(gA1 + 4);
            float4 pb0l = *(const float4*)(gB0),     pb0h = *(const float4*)(gB0 + 4);
            float4 pb1l = *(const float4*)(gB1),     pb1h = *(const float4*)(gB1 + 4);
            for (int k0 = 0; k0 < D_DIM; k0 += 64) {
                *(bf16x8*)&At[cur][r0][o0] = cvt8(pa0l, pa0h);
                *(bf16x8*)&At[cur][r1][o1] = cvt8(pa1l, pa1h);
                *(bf16x8*)&Bt[cur][r0][o0] = cvt8(pb0l, pb0h);
                *(bf16x8*)&Bt[cur][r1][o1] = cvt8(pb1l, pb1h);
                if (k0 + 64 < D_DIM) {
                    pa0l = *(const float4*)(gA0 + k0 + 64); pa0h = *(const float4*)(gA0 + k0 + 68);
                    pa1l = *(const float4*)(gA1 + k0 + 64); pa1h = *(const float4*)(gA1 + k0 + 68);
                    pb0l = *(const float4*)(gB0 + k0 + 64); pb0h = *(const float4*)(gB0 + k0 + 68);
                    pb1l = *(const float4*)(gB1 + k0 + 64); pb1h = *(const float4*)(gB1 + k0 + 68);
                }
                __syncthreads();
                #pragma unroll
                for (int kc = 0; kc < 2; ++kc) {
                    bf16x8 af[2], bfr[2];
                    #pragma unroll
                    for (int tm = 0; tm < 2; ++tm) af[tm]  = *(const bf16x8*)&At[cur][wm * 32 + tm * 16 + lq][kc * 32 + quad * 8];
                    #pragma unroll
                    for (int tn = 0; tn < 2; ++tn) bfr[tn] = *(const bf16x8*)&Bt[cur][wn * 32 + tn * 16 + lq][kc * 32 + quad * 8];
                    #pragma unroll
                    for (int tm = 0; tm < 2; ++tm)
                        #pragma unroll
                        for (int tn = 0; tn < 2; ++tn)
                            acc[tm][tn] = __builtin_amdgcn_mfma_f32_16x16x32_bf16(af[tm], bfr[tn], acc[tm][tn], 0, 0, 0);
                }
                cur ^= 1;
            }
        } else {
            const bf16* gA0 = X + (size_t)(rowBase + r0) * D_DIM + o0;
            const bf16* gA1 = X + (size_t)(rowBase + r1) * D_DIM + o1;
            const bf16* gB0 = W + (size_t)(colBase + r0) * D_DIM + o0;
            const bf16* gB1 = W + (size_t)(colBase + r1) * D_DIM + o1;
            char* baseA = (char*)&At[0][0][0];
            char* baseB = (char*)&Bt[0][0][0];
            GLOAD_LDS16(gA0, baseA + wave * 1024);
            GLOAD_LDS16(gA1, baseA + 4096 + wave * 1024);
            GLOAD_LDS16(gB0, baseB + wave * 1024);
            GLOAD_LDS16(gB1, baseB + 4096 + wave * 1024);
            for (int k0 = 0; k0 < D_DIM; k0 += 64) {
                __syncthreads();
                if (k0 + 64 < D_DIM) {                  // issue AFTER barrier: overlaps compute
                    int nb = (cur ^ 1) * 8192;
                    GLOAD_LDS16(gA0 + k0 + 64, baseA + nb + wave * 1024);
                    GLOAD_LDS16(gA1 + k0 + 64, baseA + nb + 4096 + wave * 1024);
                    GLOAD_LDS16(gB0 + k0 + 64, baseB + nb + wave * 1024);
                    GLOAD_LDS16(gB1 + k0 + 64, baseB + nb + 4096 + wave * 1024);
                }
                #pragma unroll
                for (int kc = 0; kc < 2; ++kc) {
                    bf16x8 af[2], bfr[2];
                    #pragma unroll
                    for (int tm = 0; tm < 2; ++tm) af[tm]  = *(const bf16x8*)&At[cur][wm * 32 + tm * 16 + lq][kc * 32 + quad * 8];
                    #pragma unroll
                    for (int tn = 0; tn < 2; ++tn) bfr[tn] = *(const bf16x8*)&Bt[cur][wn * 32 + tn * 16 + lq][kc * 32 + quad * 8];
                    #pragma unroll
                    for (int tm = 0; tm < 2; ++tm)
                        #pragma unroll
                        for (int tn = 0; tn < 2; ++tn)
                            acc[tm][tn] = __builtin_amdgcn_mfma_f32_16x16x32_bf16(af[tm], bfr[tn], acc[tm][tn], 0, 0, 0);
                }
                cur ^= 1;
            }
        }

        const float a = slope[0];
        if (MODE == 2) {
            float wo[2];
            #pragma unroll
            for (int tn = 0; tn < 2; ++tn) wo[tn] = Wo[colBase + wn * 32 + tn * 16 + lq];
            #pragma unroll
            for (int tm = 0; tm < 2; ++tm) {
                #pragma unroll
                for (int r = 0; r < 4; ++r) {
                    float p = 0.f;
                    #pragma unroll
                    for (int tn = 0; tn < 2; ++tn) {
                        float v = acc[tm][tn][r];
                        v = (v >= 0.f) ? v : a * v;
                        p += v * wo[tn];
                    }
                    #pragma unroll
                    for (int m = 1; m < 16; m <<= 1) p += __shfl_xor(p, m, 64);
                    if (lq == 0)
                        atomicAdd(&ang[rowBase + wm * 32 + tm * 16 + quad * 4 + r], p);
                }
            }
        } else {
            #pragma unroll
            for (int tm = 0; tm < 2; ++tm) {
                #pragma unroll
                for (int tn = 0; tn < 2; ++tn) {
                    int col = colBase + wn * 32 + tn * 16 + lq;
                    float b = (MODE == 0) ? bias[col] : 0.f;
                    #pragma unroll
                    for (int r = 0; r < 4; ++r) {
                        int row = rowBase + wm * 32 + tm * 16 + quad * 4 + r;
                        float v = acc[tm][tn][r] + b;
                        v = (v >= 0.f) ? v : a * v;
                        outB[(size_t)row * D_DIM + col] = (bf16)v;
                    }
                }
            }
        }
    } else if (MODE == 0) {
        if (bx < 640) {
            int base = (bx - 512) * 256 + t;
            for (int e = base; e < E_EDGES; e += 128 * 256) {
                int r = esrc[e], c = edst[e];
                atomicOr(&AbOut[(size_t)r * NWORDS + (c >> 5)], 1u << (c & 31));
            }
        } else if (bx < 768) {
            int cb = bx - 640;
            const float* src = (cb < 64) ? W1f : W2f;
            bf16* dst = (cb < 64) ? W1b : W2b;
            size_t base = (size_t)(cb & 63) * 4096;
            #pragma unroll
            for (int i = 0; i < 4; ++i) {
                size_t e = base + (size_t)(i * 256 + t) * 4;
                float4 v = *(const float4*)(src + e);
                bf16x4 o; o.x = (bf16)v.x; o.y = (bf16)v.y; o.z = (bf16)v.z; o.w = (bf16)v.w;
                *(bf16x4*)(dst + e) = o;
            }
        } else {
            float b = bo[0];
            for (int i = t; i < N_NODES; i += 256) { ang[i] = b; h1[i] = 0.f; }
        }
    } else {
        // boolean row-OR: BOut[i] = OR_{j in P-row(i)} Q-row(j). One row/wave, 1024 tail blocks.
        int row = (bx - 512) * 4 + wave;
        if (lane == 0) s_cnt[wave] = 0;
        __syncthreads();
        const u32* prow = P + (size_t)row * NWORDS;
        #pragma unroll
        for (int h = 0; h < 2; ++h) {
            u32 bits = prow[h * 64 + lane];
            int base = (h * 64 + lane) * 32;
            while (bits) {
                int b = __ffs(bits) - 1; bits &= bits - 1;
                int pos = atomicAdd(&s_cnt[wave], 1);
                if (pos < 256) s_list[wave][pos] = base + b;
            }
        }
        __syncthreads();
        int cnt = min(s_cnt[wave], 256);
        u32 acc0 = 0, acc1 = 0;
        int j = 0;
        for (; j + 4 <= cnt; j += 4) {
            int i0 = s_list[wave][j], i1 = s_list[wave][j + 1];
            int i2 = s_list[wave][j + 2], i3 = s_list[wave][j + 3];
            const u32* q0 = Q + (size_t)i0 * NWORDS;
            const u32* q1 = Q + (size_t)i1 * NWORDS;
            const u32* q2 = Q + (size_t)i2 * NWORDS;
            const u32* q3 = Q + (size_t)i3 * NWORDS;
            u32 x0 = q0[lane], x1 = q1[lane], x2 = q2[lane], x3 = q3[lane];
            u32 y0 = q0[64 + lane], y1 = q1[64 + lane], y2 = q2[64 + lane], y3 = q3[64 + lane];
            acc0 |= x0 | x1 | x2 | x3;
            acc1 |= y0 | y1 | y2 | y3;
        }
        for (; j < cnt; ++j) {
            const u32* q = Q + (size_t)s_list[wave][j] * NWORDS;
            acc0 |= q[lane]; acc1 |= q[64 + lane];
        }
        BOut[(size_t)row * NWORDS + lane]      = acc0;
        BOut[(size_t)row * NWORDS + 64 + lane] = acc1;
    }
}

// ---------------- aggregate: hop1 -> barrier -> bmv2 -> barrier -> bmv3 ----------------
// Merges 3 serial dispatches into 1 using manual device-scope barriers (saves 2 boundaries).
__global__ __launch_bounds__(256)
void aggregate(const int* __restrict__ esrc, const int* __restrict__ edst,
               const float* __restrict__ ang, float* __restrict__ h1,
               const u32* __restrict__ A2, const u32* __restrict__ A3,
               float* __restrict__ a2v, float* __restrict__ Tp,
               u32* __restrict__ ctr, float* __restrict__ out)
{
    __shared__ float s_red[4];
    const int bx = blockIdx.x;
    const int t = threadIdx.x;
    const int wave = t >> 6, lane = t & 63;

    // ===== Phase 1: hop1 raw-edge scatter (duplicates count) =====
    if (t < 128) {
        int e = bx * 128 + t;                     // 1024 x 128 = E_EDGES
        atomicAdd(&h1[esrc[e]], 0.25f * ang[edst[e]]);
    }
    grid_barrier(&ctr[0]);

    // ===== Phase 2: a2 = a1 + (1/9)*A2@a1, a1(x)=ang[x]+h1[x]; Tpart[bx] = block sum =====
    {
        int row = bx * 4 + wave;
        float s = 0.f;
        #pragma unroll
        for (int h = 0; h < 2; ++h) {
            u32 bits = A2[(size_t)row * NWORDS + h * 64 + lane];
            int base = (h * 64 + lane) * 32;
            while (bits) {
                int b = __ffs(bits) - 1; bits &= bits - 1;
                s += ang[base + b] + h1[base + b];
            }
        }
        #pragma unroll
        for (int off = 32; off > 0; off >>= 1) s += __shfl_down(s, off, 64);
        if (lane == 0) {
            float val = (ang[row] + h1[row]) + (1.f / 9.f) * s;
            a2v[row] = val;
            s_red[wave] = val;
        }
        __syncthreads();
        if (t == 0) Tp[bx] = s_red[0] + s_red[1] + s_red[2] + s_red[3];
    }
    grid_barrier(&ctr[16]);     // separate cacheline

    // ===== Phase 3: out = a2 + (1/16)*(T - complement-sum); A3 ~97% dense =====
    {
        float tsum = 0.f;
        #pragma unroll
        for (int i = 0; i < 4; ++i) tsum += Tp[i * 256 + t];
        #pragma unroll
        for (int off = 32; off > 0; off >>= 1) tsum += __shfl_down(tsum, off, 64);
        __syncthreads();                          // s_red reuse hazard vs phase 2
        if (lane == 0) s_red[wave] = tsum;
        __syncthreads();
        const float T = s_red[0] + s_red[1] + s_red[2] + s_red[3];

        int row = bx * 4 + wave;
        float s = 0.f;
        #pragma unroll
        for (int h = 0; h < 2; ++h) {
            u32 bits = ~A3[(size_t)row * NWORDS + h * 64 + lane];   // complement
            int base = (h * 64 + lane) * 32;
            while (bits) {
                int b = __ffs(bits) - 1; bits &= bits - 1;
                s += a2v[base + b];
            }
        }
        #pragma unroll
        for (int off = 32; off > 0; off >>= 1) s += __shfl_down(s, off, 64);
        if (lane == 0) out[row] = a2v[row] + (1.f / 16.f) * (T - s);
    }
}

extern "C" void kernel_launch(void* const* d_in, const int* in_sizes, int n_in,
                              void* d_out, int out_size, void* d_ws, size_t ws_size,
                              hipStream_t stream) {
    const float* coeffs = (const float*)d_in[0];
    const int*   edges  = (const int*)d_in[1];
    const float* W0     = (const float*)d_in[2];
    const float* b0     = (const float*)d_in[3];
    const float* pa0    = (const float*)d_in[4];
    const float* W1     = (const float*)d_in[5];
    const float* pa1    = (const float*)d_in[6];
    const float* W2     = (const float*)d_in[7];
    const float* pa2    = (const float*)d_in[8];
    const float* Wo     = (const float*)d_in[9];
    const float* bo     = (const float*)d_in[10];
    float* out = (float*)d_out;

    char* ws = (char*)d_ws;
    bf16*  W1b  = (bf16*)(ws + OFF_W1B);
    bf16*  W2b  = (bf16*)(ws + OFF_W2B);
    bf16*  x1b  = (bf16*)(ws + OFF_X1);
    bf16*  x2b  = (bf16*)(ws + OFF_X2);
    float* ang  = (float*)(ws + OFF_ANG);
    float* h1   = (float*)(ws + OFF_H1);
    float* a2v  = (float*)(ws + OFF_A2V);
    float* Tp   = (float*)(ws + OFF_TP);
    u32*   ctr  = (u32*)(ws + OFF_CTR);
    u32*   Ab   = (u32*)(ws + OFF_AB);
    u32*   A2b  = (u32*)(ws + OFF_A2B);
    u32*   A3b  = (u32*)(ws + OFF_A3B);

    const int* srcp = edges;
    const int* dstp = edges + E_EDGES;

    // zero barrier counters + Ab (contiguous; ws is poisoned 0xAA each call)
    hipMemsetAsync(ws + OFF_CTR, 0, ZERO_BYTES, stream);

    // GEMM0 (inline fp32 cast, reg-prefetch dbuf) + build_adj + cast W1/W2 + init ang/h1
    gemm_fused<0><<<769, 256, 0, stream>>>(coeffs, W0, nullptr, nullptr, x1b, b0, pa0,
                                           nullptr, ang, bo, h1, W1, W2, W1b, W2b,
                                           srcp, dstp, Ab, nullptr, nullptr, nullptr);
    // GEMM1 (lds dbuf) + A2 = bool(A@A)
    gemm_fused<1><<<1536, 256, 0, stream>>>(nullptr, nullptr, x1b, W1b, x2b, nullptr, pa1,
                                            nullptr, nullptr, nullptr, nullptr, nullptr, nullptr,
                                            nullptr, nullptr, nullptr, nullptr, nullptr, Ab, Ab, A2b);
    // GEMM2 (lds dbuf, fused @Wo -> ang) + A3 = bool(A@A2)
    gemm_fused<2><<<1536, 256, 0, stream>>>(nullptr, nullptr, x2b, W2b, nullptr, nullptr, pa2,
                                            Wo, ang, nullptr, nullptr, nullptr, nullptr, nullptr, nullptr,
                                            nullptr, nullptr, nullptr, Ab, A2b, A3b);

    // hop1 -> bmv2 -> bmv3 in one dispatch (manual grid barriers)
    aggregate<<<AGG_BLOCKS, 256, 0, stream>>>(srcp, dstp, ang, h1, A2b, A3b, a2v, Tp, ctr, out);
}

// Round 11
// 146.811 us; speedup vs baseline: 1.7210x; 1.7210x over previous
//
#include <hip/hip_runtime.h>

#define N_NODES 4096
#define D_DIM   512
#define E_EDGES 131072
#define NWORDS  128   // 4096/32

typedef __bf16 bf16;
typedef __bf16 bf16x4 __attribute__((ext_vector_type(4)));
typedef __bf16 bf16x8 __attribute__((ext_vector_type(8)));
typedef float  f32x4  __attribute__((ext_vector_type(4)));
typedef unsigned int u32;

// async global->LDS, 16 B per lane; LDS dest = wave-uniform base + lane*16
#define GLOAD_LDS16(gp, lp) \
    __builtin_amdgcn_global_load_lds((const __attribute__((address_space(1))) u32*)(gp), \
                                     (__attribute__((address_space(3))) u32*)(lp), 16, 0, 0)

// ---------------- workspace layout ----------------
static const size_t OFF_W1B = 0;                                    // W1 bf16 512 KiB
static const size_t OFF_W2B = OFF_W1B + (size_t)D_DIM*D_DIM*2;
static const size_t OFF_X1  = OFF_W2B + (size_t)D_DIM*D_DIM*2;      // x1 bf16 4 MiB
static const size_t OFF_X2  = OFF_X1  + (size_t)N_NODES*D_DIM*2;    // x2 bf16 4 MiB
static const size_t OFF_ANG = OFF_X2  + (size_t)N_NODES*D_DIM*2;    // angles fp32 (init bo, atomic partials)
static const size_t OFF_H1  = OFF_ANG + N_NODES*4;                  // hop1 accum (carries 0.25)
static const size_t OFF_A2V = OFF_H1  + N_NODES*4;                  // a2 fp32
static const size_t OFF_TP  = OFF_A2V + N_NODES*4;                  // Tpart[1024]
static const size_t OFF_AB  = OFF_TP  + 1024*4;                     // A bits 2 MiB
static const size_t OFF_A2B = OFF_AB  + (size_t)N_NODES*NWORDS*4;   // A^2 bits
static const size_t OFF_A3B = OFF_A2B + (size_t)N_NODES*NWORDS*4;   // A^3 bits

__device__ __forceinline__ bf16x8 cvt8(float4 lo, float4 hi) {
    bf16x8 r;
    r[0] = (bf16)lo.x; r[1] = (bf16)lo.y; r[2] = (bf16)lo.z; r[3] = (bf16)lo.w;
    r[4] = (bf16)hi.x; r[5] = (bf16)hi.y; r[6] = (bf16)hi.z; r[7] = (bf16)hi.w;
    return r;
}

// ---------------- fused GEMM (+independent work in tail blocks) ----------------
// Tile 64x64, BK=64, double-buffered LDS (loads for slab k+1 issued AFTER the barrier
// so the barrier's vmcnt-drain doesn't serialize them). 512 gemm blocks, 4 waves.
// MODE 0: fp32 inputs, register-prefetch + inline cast; tail = adj(128)+Wcast(128)+init(1).
// MODE 1/2: bf16 inputs via global_load_lds; tail = 1024 boolean row-OR blocks.
// NOTE (r8/r10): do NOT fuse the serial chain with grid-wide sync — cooperative
// grid.sync measured ~106us, manual RMW-spin barrier ~65us; a dispatch boundary is ~4us.
template<int MODE>
__global__ __launch_bounds__(256)
void gemm_fused(const float* __restrict__ Xf, const float* __restrict__ Wf,   // MODE 0
                const bf16* __restrict__ X, const bf16* __restrict__ W,       // MODE 1/2
                bf16* __restrict__ outB,
                const float* __restrict__ bias, const float* __restrict__ slope,
                const float* __restrict__ Wo, float* __restrict__ ang,
                const float* __restrict__ bo, float* __restrict__ h1,
                const float* __restrict__ W1f, const float* __restrict__ W2f,
                bf16* __restrict__ W1b, bf16* __restrict__ W2b,
                const int* __restrict__ esrc, const int* __restrict__ edst,
                u32* __restrict__ AbOut,
                const u32* __restrict__ P, const u32* __restrict__ Q, u32* __restrict__ BOut)
{
    __shared__ bf16 At[2][64][64];   // 16 KiB (double-buffered)
    __shared__ bf16 Bt[2][64][64];   // 16 KiB
    __shared__ int  s_cnt[4];
    __shared__ int  s_list[4][256];
    const int bx = blockIdx.x;
    const int t = threadIdx.x;
    const int wave = t >> 6, lane = t & 63;

    if (bx < 512) {
        const int wm = wave >> 1, wn = wave & 1;
        const int quad = lane >> 4, lq = lane & 15;
        const int rowBase = (bx >> 3) * 64;
        const int colBase = (bx & 7) * 64;
        const int c0 = t, c1 = t + 256;                 // 512 chunks of 8 elems per tile
        const int r0 = c0 >> 3, o0 = (c0 & 7) * 8;
        const int r1 = c1 >> 3, o1 = (c1 & 7) * 8;

        f32x4 acc[2][2] = {};
        int cur = 0;

        if (MODE == 0) {
            const float* gA0 = Xf + (size_t)(rowBase + r0) * D_DIM + o0;
            const float* gA1 = Xf + (size_t)(rowBase + r1) * D_DIM + o1;
            const float* gB0 = Wf + (size_t)(colBase + r0) * D_DIM + o0;
            const float* gB1 = Wf + (size_t)(colBase + r1) * D_DIM + o1;
            float4 pa0l = *(const float4*)(gA0),     pa0h = *(const float4*)(gA0 + 4);
            float4 pa1l = *(const float4*)(gA1),     pa1h = *(const float4*)(gA1 + 4);
            float4 pb0l = *(const float4*)(gB0),     pb0h = *(const float4*)(gB0 + 4);
            float4 pb1l = *(const float4*)(gB1),     pb1h = *(const float4*)(gB1 + 4);
            for (int k0 = 0; k0 < D_DIM; k0 += 64) {
                *(bf16x8*)&At[cur][r0][o0] = cvt8(pa0l, pa0h);
                *(bf16x8*)&At[cur][r1][o1] = cvt8(pa1l, pa1h);
                *(bf16x8*)&Bt[cur][r0][o0] = cvt8(pb0l, pb0h);
                *(bf16x8*)&Bt[cur][r1][o1] = cvt8(pb1l, pb1h);
                if (k0 + 64 < D_DIM) {
                    pa0l = *(const float4*)(gA0 + k0 + 64); pa0h = *(const float4*)(gA0 + k0 + 68);
                    pa1l = *(const float4*)(gA1 + k0 + 64); pa1h = *(const float4*)(gA1 + k0 + 68);
                    pb0l = *(const float4*)(gB0 + k0 + 64); pb0h = *(const float4*)(gB0 + k0 + 68);
                    pb1l = *(const float4*)(gB1 + k0 + 64); pb1h = *(const float4*)(gB1 + k0 + 68);
                }
                __syncthreads();
                #pragma unroll
                for (int kc = 0; kc < 2; ++kc) {
                    bf16x8 af[2], bfr[2];
                    #pragma unroll
                    for (int tm = 0; tm < 2; ++tm) af[tm]  = *(const bf16x8*)&At[cur][wm * 32 + tm * 16 + lq][kc * 32 + quad * 8];
                    #pragma unroll
                    for (int tn = 0; tn < 2; ++tn) bfr[tn] = *(const bf16x8*)&Bt[cur][wn * 32 + tn * 16 + lq][kc * 32 + quad * 8];
                    #pragma unroll
                    for (int tm = 0; tm < 2; ++tm)
                        #pragma unroll
                        for (int tn = 0; tn < 2; ++tn)
                            acc[tm][tn] = __builtin_amdgcn_mfma_f32_16x16x32_bf16(af[tm], bfr[tn], acc[tm][tn], 0, 0, 0);
                }
                cur ^= 1;
            }
        } else {
            const bf16* gA0 = X + (size_t)(rowBase + r0) * D_DIM + o0;
            const bf16* gA1 = X + (size_t)(rowBase + r1) * D_DIM + o1;
            const bf16* gB0 = W + (size_t)(colBase + r0) * D_DIM + o0;
            const bf16* gB1 = W + (size_t)(colBase + r1) * D_DIM + o1;
            char* baseA = (char*)&At[0][0][0];
            char* baseB = (char*)&Bt[0][0][0];
            GLOAD_LDS16(gA0, baseA + wave * 1024);
            GLOAD_LDS16(gA1, baseA + 4096 + wave * 1024);
            GLOAD_LDS16(gB0, baseB + wave * 1024);
            GLOAD_LDS16(gB1, baseB + 4096 + wave * 1024);
            for (int k0 = 0; k0 < D_DIM; k0 += 64) {
                __syncthreads();
                if (k0 + 64 < D_DIM) {                  // issue AFTER barrier: overlaps compute
                    int nb = (cur ^ 1) * 8192;
                    GLOAD_LDS16(gA0 + k0 + 64, baseA + nb + wave * 1024);
                    GLOAD_LDS16(gA1 + k0 + 64, baseA + nb + 4096 + wave * 1024);
                    GLOAD_LDS16(gB0 + k0 + 64, baseB + nb + wave * 1024);
                    GLOAD_LDS16(gB1 + k0 + 64, baseB + nb + 4096 + wave * 1024);
                }
                #pragma unroll
                for (int kc = 0; kc < 2; ++kc) {
                    bf16x8 af[2], bfr[2];
                    #pragma unroll
                    for (int tm = 0; tm < 2; ++tm) af[tm]  = *(const bf16x8*)&At[cur][wm * 32 + tm * 16 + lq][kc * 32 + quad * 8];
                    #pragma unroll
                    for (int tn = 0; tn < 2; ++tn) bfr[tn] = *(const bf16x8*)&Bt[cur][wn * 32 + tn * 16 + lq][kc * 32 + quad * 8];
                    #pragma unroll
                    for (int tm = 0; tm < 2; ++tm)
                        #pragma unroll
                        for (int tn = 0; tn < 2; ++tn)
                            acc[tm][tn] = __builtin_amdgcn_mfma_f32_16x16x32_bf16(af[tm], bfr[tn], acc[tm][tn], 0, 0, 0);
                }
                cur ^= 1;
            }
        }

        const float a = slope[0];
        if (MODE == 2) {
            // fused [512 -> 1] projection: dot with Wo cols, reduce, atomic partial into ang
            float wo[2];
            #pragma unroll
            for (int tn = 0; tn < 2; ++tn) wo[tn] = Wo[colBase + wn * 32 + tn * 16 + lq];
            #pragma unroll
            for (int tm = 0; tm < 2; ++tm) {
                #pragma unroll
                for (int r = 0; r < 4; ++r) {
                    float p = 0.f;
                    #pragma unroll
                    for (int tn = 0; tn < 2; ++tn) {
                        float v = acc[tm][tn][r];
                        v = (v >= 0.f) ? v : a * v;
                        p += v * wo[tn];
                    }
                    #pragma unroll
                    for (int m = 1; m < 16; m <<= 1) p += __shfl_xor(p, m, 64);
                    if (lq == 0)
                        atomicAdd(&ang[rowBase + wm * 32 + tm * 16 + quad * 4 + r], p);
                }
            }
        } else {
            #pragma unroll
            for (int tm = 0; tm < 2; ++tm) {
                #pragma unroll
                for (int tn = 0; tn < 2; ++tn) {
                    int col = colBase + wn * 32 + tn * 16 + lq;
                    float b = (MODE == 0) ? bias[col] : 0.f;
                    #pragma unroll
                    for (int r = 0; r < 4; ++r) {
                        int row = rowBase + wm * 32 + tm * 16 + quad * 4 + r;
                        float v = acc[tm][tn][r] + b;
                        v = (v >= 0.f) ? v : a * v;
                        outB[(size_t)row * D_DIM + col] = (bf16)v;
                    }
                }
            }
        }
    } else if (MODE == 0) {
        if (bx < 640) {
            // build boolean adjacency bits — 128 blocks
            int base = (bx - 512) * 256 + t;
            for (int e = base; e < E_EDGES; e += 128 * 256) {
                int r = esrc[e], c = edst[e];
                atomicOr(&AbOut[(size_t)r * NWORDS + (c >> 5)], 1u << (c & 31));
            }
        } else if (bx < 768) {
            // cast W1, W2 to bf16 — 128 blocks (64 each), 4096 floats/block
            int cb = bx - 640;
            const float* src = (cb < 64) ? W1f : W2f;
            bf16* dst = (cb < 64) ? W1b : W2b;
            size_t base = (size_t)(cb & 63) * 4096;
            #pragma unroll
            for (int i = 0; i < 4; ++i) {
                size_t e = base + (size_t)(i * 256 + t) * 4;
                float4 v = *(const float4*)(src + e);
                bf16x4 o; o.x = (bf16)v.x; o.y = (bf16)v.y; o.z = (bf16)v.z; o.w = (bf16)v.w;
                *(bf16x4*)(dst + e) = o;
            }
        } else {
            // init ang=bo, h1=0 (ang must be seeded before g2's atomic partials)
            float b = bo[0];
            for (int i = t; i < N_NODES; i += 256) { ang[i] = b; h1[i] = 0.f; }
        }
    } else {
        // boolean row-OR: BOut[i] = OR_{j in P-row(i)} Q-row(j). One row/wave, 1024 tail blocks.
        // P rows are A rows (~32 bits) -> 256-entry list never overflows.
        int row = (bx - 512) * 4 + wave;
        if (lane == 0) s_cnt[wave] = 0;
        __syncthreads();
        const u32* prow = P + (size_t)row * NWORDS;
        #pragma unroll
        for (int h = 0; h < 2; ++h) {
            u32 bits = prow[h * 64 + lane];
            int base = (h * 64 + lane) * 32;
            while (bits) {
                int b = __ffs(bits) - 1; bits &= bits - 1;
                int pos = atomicAdd(&s_cnt[wave], 1);
                if (pos < 256) s_list[wave][pos] = base + b;
            }
        }
        __syncthreads();
        int cnt = min(s_cnt[wave], 256);
        u32 acc0 = 0, acc1 = 0;
        int j = 0;
        for (; j + 4 <= cnt; j += 4) {               // 8 independent loads in flight
            int i0 = s_list[wave][j], i1 = s_list[wave][j + 1];
            int i2 = s_list[wave][j + 2], i3 = s_list[wave][j + 3];
            const u32* q0 = Q + (size_t)i0 * NWORDS;
            const u32* q1 = Q + (size_t)i1 * NWORDS;
            const u32* q2 = Q + (size_t)i2 * NWORDS;
            const u32* q3 = Q + (size_t)i3 * NWORDS;
            u32 x0 = q0[lane], x1 = q1[lane], x2 = q2[lane], x3 = q3[lane];
            u32 y0 = q0[64 + lane], y1 = q1[64 + lane], y2 = q2[64 + lane], y3 = q3[64 + lane];
            acc0 |= x0 | x1 | x2 | x3;
            acc1 |= y0 | y1 | y2 | y3;
        }
        for (; j < cnt; ++j) {
            const u32* q = Q + (size_t)s_list[wave][j] * NWORDS;
            acc0 |= q[lane]; acc1 |= q[64 + lane];
        }
        BOut[(size_t)row * NWORDS + lane]      = acc0;
        BOut[(size_t)row * NWORDS + 64 + lane] = acc1;
    }
}

// ---------------- hop 1: raw edge list scatter (duplicates count) into h1 ----------------
__global__ __launch_bounds__(256)
void hop1_edges(const int* __restrict__ src, const int* __restrict__ dst,
                const float* __restrict__ ang, float* __restrict__ h1)
{
    int e = blockIdx.x * 256 + threadIdx.x;
    if (e < E_EDGES) atomicAdd(&h1[src[e]], 0.25f * ang[dst[e]]);
}

// ---------------- a2[i] = a1(i) + (1/9) * sum_{j in A2-row(i)} a1(j); a1(x)=ang[x]+h1[x] ----------------
// Also emits per-block partial sums of a2 (for bmv3's dense-complement trick).
__global__ __launch_bounds__(256)
void bits_matvec2(const u32* __restrict__ A2, const float* __restrict__ ang,
                  const float* __restrict__ h1, float* __restrict__ a2,
                  float* __restrict__ Tpart)
{
    __shared__ float s_red[4];
    int wave = threadIdx.x >> 6, lane = threadIdx.x & 63;
    int row  = blockIdx.x * 4 + wave;
    float s = 0.f;
    #pragma unroll
    for (int h = 0; h < 2; ++h) {
        u32 bits = A2[(size_t)row * NWORDS + h * 64 + lane];
        int base = (h * 64 + lane) * 32;
        while (bits) {
            int b = __ffs(bits) - 1;
            bits &= bits - 1;
            s += ang[base + b] + h1[base + b];
        }
    }
    #pragma unroll
    for (int off = 32; off > 0; off >>= 1) s += __shfl_down(s, off, 64);
    if (lane == 0) {
        float val = (ang[row] + h1[row]) + (1.f / 9.f) * s;
        a2[row] = val;
        s_red[wave] = val;
    }
    __syncthreads();
    if (threadIdx.x == 0)
        Tpart[blockIdx.x] = s_red[0] + s_red[1] + s_red[2] + s_red[3];
}

// ---------------- out[i] = a2[i] + (1/16) * (T - sum_{j NOT in A3-row(i)} a2[j]) ----------------
// A3 is ~97% dense: gather the ~100-bit complement instead of ~4000 set bits.
__global__ __launch_bounds__(256)
void bits_matvec3(const u32* __restrict__ A3, const float* __restrict__ a2,
                  const float* __restrict__ Tpart, float* __restrict__ out)
{
    __shared__ float s_part[4];
    int wave = threadIdx.x >> 6, lane = threadIdx.x & 63;

    float tsum = 0.f;
    #pragma unroll
    for (int i = 0; i < 4; ++i) tsum += Tpart[i * 256 + threadIdx.x];
    #pragma unroll
    for (int off = 32; off > 0; off >>= 1) tsum += __shfl_down(tsum, off, 64);
    if (lane == 0) s_part[wave] = tsum;
    __syncthreads();
    const float T = s_part[0] + s_part[1] + s_part[2] + s_part[3];

    int row = blockIdx.x * 4 + wave;
    float s = 0.f;
    #pragma unroll
    for (int h = 0; h < 2; ++h) {
        u32 bits = ~A3[(size_t)row * NWORDS + h * 64 + lane];   // complement
        int base = (h * 64 + lane) * 32;
        while (bits) {
            int b = __ffs(bits) - 1;
            bits &= bits - 1;
            s += a2[base + b];
        }
    }
    #pragma unroll
    for (int off = 32; off > 0; off >>= 1) s += __shfl_down(s, off, 64);
    if (lane == 0) out[row] = a2[row] + (1.f / 16.f) * (T - s);
}

extern "C" void kernel_launch(void* const* d_in, const int* in_sizes, int n_in,
                              void* d_out, int out_size, void* d_ws, size_t ws_size,
                              hipStream_t stream) {
    const float* coeffs = (const float*)d_in[0];
    const int*   edges  = (const int*)d_in[1];
    const float* W0     = (const float*)d_in[2];
    const float* b0     = (const float*)d_in[3];
    const float* pa0    = (const float*)d_in[4];
    const float* W1     = (const float*)d_in[5];
    const float* pa1    = (const float*)d_in[6];
    const float* W2     = (const float*)d_in[7];
    const float* pa2    = (const float*)d_in[8];
    const float* Wo     = (const float*)d_in[9];
    const float* bo     = (const float*)d_in[10];
    float* out = (float*)d_out;

    char* ws = (char*)d_ws;
    bf16*  W1b  = (bf16*)(ws + OFF_W1B);
    bf16*  W2b  = (bf16*)(ws + OFF_W2B);
    bf16*  x1b  = (bf16*)(ws + OFF_X1);
    bf16*  x2b  = (bf16*)(ws + OFF_X2);
    float* ang  = (float*)(ws + OFF_ANG);
    float* h1   = (float*)(ws + OFF_H1);
    float* a2v  = (float*)(ws + OFF_A2V);
    float* Tp   = (float*)(ws + OFF_TP);
    u32*   Ab   = (u32*)(ws + OFF_AB);
    u32*   A2b  = (u32*)(ws + OFF_A2B);
    u32*   A3b  = (u32*)(ws + OFF_A3B);

    const int* srcp = edges;
    const int* dstp = edges + E_EDGES;

    // zero Ab before build_adj atomics (ws is poisoned 0xAA each call)
    hipMemsetAsync(Ab, 0, (size_t)N_NODES * NWORDS * 4, stream);

    // GEMM0 (inline fp32 cast, reg-prefetch dbuf) + build_adj + cast W1/W2 + init ang/h1
    gemm_fused<0><<<769, 256, 0, stream>>>(coeffs, W0, nullptr, nullptr, x1b, b0, pa0,
                                           nullptr, ang, bo, h1, W1, W2, W1b, W2b,
                                           srcp, dstp, Ab, nullptr, nullptr, nullptr);
    // GEMM1 (lds dbuf) + A2 = bool(A@A)
    gemm_fused<1><<<1536, 256, 0, stream>>>(nullptr, nullptr, x1b, W1b, x2b, nullptr, pa1,
                                            nullptr, nullptr, nullptr, nullptr, nullptr, nullptr,
                                            nullptr, nullptr, nullptr, nullptr, nullptr, Ab, Ab, A2b);
    // GEMM2 (lds dbuf, fused @Wo -> ang) + A3 = bool(A@A2)
    gemm_fused<2><<<1536, 256, 0, stream>>>(nullptr, nullptr, x2b, W2b, nullptr, nullptr, pa2,
                                            Wo, ang, nullptr, nullptr, nullptr, nullptr, nullptr, nullptr,
                                            nullptr, nullptr, nullptr, Ab, A2b, A3b);

    hop1_edges<<<E_EDGES / 256, 256, 0, stream>>>(srcp, dstp, ang, h1);
    bits_matvec2<<<N_NODES / 4, 256, 0, stream>>>(A2b, ang, h1, a2v, Tp);
    bits_matvec3<<<N_NODES / 4, 256, 0, stream>>>(A3b, a2v, Tp, out);
}